// Round 3
// baseline (93.768 us; speedup 1.0000x reference)
//
#include <hip/hip_runtime.h>
#include <hip/hip_bf16.h>

// LocalCausalAttention: B=2, N=2048, D=1024, H=16, DH=64, WINDOW=64
// out = ( softmax(mask(QK^T*0.125)) V ) Wout^T + bout,  QKV = x Wqkv^T + bqkv
//
// R3: true counted-vmcnt pipeline for the 256^2 QKV GEMM (T2+T3+T4+T5):
//   per K-tile t (4 phases, 16 MFMA each, 24 ds_read_b128/wave total):
//     p0: stage B0+B1(t+1)->Bs[nxt] ; read af[0..3](t) ; bar ; MFMA a=0,1 ; bar
//     p1: read af[4..7](t)          ; bar ; MFMA a=2,3 ; bar
//     p2: stage A0(t+2)->As[cur]    ; bar ; MFMA a=4,5 ; vmcnt(2) ; bar
//     p3: stage A1(t+2)->As[cur]    ; bar ; MFMA a=6,7 ; re-read bq<-B(t+1) ; vmcnt(4) ; bar
//   B-frags held in registers for the whole tile (read once at p3 of t-1).
//   vmcnt(2)@p2 validates B(t+1) (staged 2.7 phases earlier, A0(t+2) allowed in flight);
//   vmcnt(4)@p3 validates A(t+1) (staged 4-6 phases earlier, A(t+2) allowed in flight).
//   Never vmcnt(0) in steady state (t==14 tail uses 0 since its allowance is vacant).
//   Raw s_barrier only (no __syncthreads: that drains vmcnt).

typedef __attribute__((ext_vector_type(8))) __bf16 bf16x8;
typedef __attribute__((ext_vector_type(4))) float f32x4;

#define GLOAD16(g, l)                                              \
  __builtin_amdgcn_global_load_lds(                                \
      (const __attribute__((address_space(1))) void*)(g),          \
      (__attribute__((address_space(3))) void*)(l), 16, 0, 0)

#define MFMA16(a, b, c) __builtin_amdgcn_mfma_f32_16x16x32_bf16((a), (b), (c), 0, 0, 0)

// ---------------- fused fp32 -> bf16 convert (x, Wqkv, Wout) ----------------
__global__ __launch_bounds__(256) void cvt3(const float* __restrict__ x,
                                            const float* __restrict__ wqkv,
                                            const float* __restrict__ wout,
                                            __bf16* __restrict__ xb,
                                            __bf16* __restrict__ wqkvb,
                                            __bf16* __restrict__ woutb) {
  const int blk = blockIdx.x;
  const float* src;
  __bf16* dst;
  int i;
  if (blk < 2048) {            // x: 4194304 elems
    src = x; dst = xb; i = (blk * 256 + (int)threadIdx.x) * 8;
  } else if (blk < 3584) {     // Wqkv: 3145728 elems
    src = wqkv; dst = wqkvb; i = ((blk - 2048) * 256 + (int)threadIdx.x) * 8;
  } else {                     // Wout: 1048576 elems
    src = wout; dst = woutb; i = ((blk - 3584) * 256 + (int)threadIdx.x) * 8;
  }
  f32x4 a = *(const f32x4*)(src + i);
  f32x4 b = *(const f32x4*)(src + i + 4);
  bf16x8 o;
  o[0] = (__bf16)a[0]; o[1] = (__bf16)a[1]; o[2] = (__bf16)a[2]; o[3] = (__bf16)a[3];
  o[4] = (__bf16)b[0]; o[5] = (__bf16)b[1]; o[6] = (__bf16)b[2]; o[7] = (__bf16)b[3];
  *(bf16x8*)(dst + i) = o;
}

// ---------------- 256^2 counted-vmcnt QKV GEMM ----------------
// C[m,n] = sum_k A[m,k]*Wqkv[n,k] + bqkv[n];  M=4096, N=3072, K=1024 hardcoded.
// 8 waves (2M x 4N), per-wave 128x64 output. Epilogue scatters to Q(*0.125)/K/V.
__global__ __launch_bounds__(512, 2) void gemm256_qkv(
    const __bf16* __restrict__ A, const __bf16* __restrict__ Bw,
    const float* __restrict__ bias,
    __bf16* __restrict__ qo, __bf16* __restrict__ ko, __bf16* __restrict__ vo) {
  constexpr int K = 1024;
  __shared__ __align__(16) unsigned char As[2][32768];  // [buf][2 halves x 128 rows x 128B]
  __shared__ __align__(16) unsigned char Bs[2][32768];
  const int tid = threadIdx.x;
  const int lane = tid & 63;
  const int wid = tid >> 6;               // 0..7
  const int wm = wid >> 2, wn = wid & 3;  // 2M x 4N wave grid
  const int colL = lane & 15, g = lane >> 4;

  // XCD-aware swizzle: 192 blocks = 24/XCD (192%8==0 -> simple form bijective)
  int s = blockIdx.x;
  s = (s & 7) * 24 + (s >> 3);
  const int m0 = (s / 12) * 256, n0 = (s % 12) * 256;

  const __bf16* A0p = A + (size_t)m0 * K;
  const __bf16* A1p = A + (size_t)(m0 + 128) * K;
  const __bf16* B0p = Bw + (size_t)n0 * K;
  const __bf16* B1p = Bw + (size_t)(n0 + 128) * K;

  // one half-tile (128 rows x 64 cols): linear LDS dest, inverse-swizzled source
  auto stage = [&](const __bf16* src, unsigned char* lds, int k0) {
#pragma unroll
    for (int it = 0; it < 2; ++it) {
      int c = tid + (it << 9);
      int row = c >> 3, pp = c & 7;
      int q = pp ^ (row & 7);
      GLOAD16(src + (size_t)row * K + k0 + (q << 3), lds + c * 16);
    }
  };

  f32x4 acc[8][4] = {};
  bf16x8 bq[4][2];  // B-frags of current tile, held across all 4 phases

  const int brow = (wn & 1) << 6;     // row offset within B-half
  const int bhalf = (wn >> 1) << 14;  // byte offset of B-half (0 or 16384)

  // prologue: tile 0 (A+B) -> buf0, A(1) -> buf1
  stage(A0p, As[0], 0);
  stage(A1p, As[0] + 16384, 0);
  stage(B0p, Bs[0], 0);
  stage(B1p, Bs[0] + 16384, 0);
  stage(A0p, As[1], 64);
  stage(A1p, As[1] + 16384, 64);
  asm volatile("s_waitcnt vmcnt(4)" ::: "memory");  // A(0),B(0) landed; A(1) in flight
  __builtin_amdgcn_s_barrier();
  {
    const unsigned char* Bb = Bs[0] + bhalf;
#pragma unroll
    for (int b = 0; b < 4; ++b) {
      const int r = brow + b * 16 + colL;
#pragma unroll
      for (int kk = 0; kk < 2; ++kk)
        bq[b][kk] = *(const bf16x8*)(Bb + r * 128 + ((((kk << 2) + g) ^ (r & 7)) << 4));
    }
  }

  for (int t = 0; t < 16; ++t) {
    const int cur = t & 1, nxt = cur ^ 1;
    const unsigned char* Ab = As[cur] + (wm << 14);
    const int k1 = (t + 1) << 6, k2 = (t + 2) << 6;
    bf16x8 af[8][2];

    // -------- phase 0: stage B(t+1); read af[0..3]; MFMA a=0,1 --------
    if (t < 15) { stage(B0p, Bs[nxt], k1); stage(B1p, Bs[nxt] + 16384, k1); }
#pragma unroll
    for (int a = 0; a < 4; ++a) {
      const int r = a * 16 + colL;
#pragma unroll
      for (int kk = 0; kk < 2; ++kk)
        af[a][kk] = *(const bf16x8*)(Ab + r * 128 + ((((kk << 2) + g) ^ (r & 7)) << 4));
    }
    __builtin_amdgcn_s_barrier();
    __builtin_amdgcn_s_setprio(1);
#pragma unroll
    for (int a = 0; a < 2; ++a)
#pragma unroll
      for (int ni = 0; ni < 4; ++ni) {
        acc[a][ni] = MFMA16(af[a][0], bq[ni][0], acc[a][ni]);
        acc[a][ni] = MFMA16(af[a][1], bq[ni][1], acc[a][ni]);
      }
    __builtin_amdgcn_s_setprio(0);
    __builtin_amdgcn_s_barrier();

    // -------- phase 1: read af[4..7]; MFMA a=2,3 --------
#pragma unroll
    for (int a = 4; a < 8; ++a) {
      const int r = a * 16 + colL;
#pragma unroll
      for (int kk = 0; kk < 2; ++kk)
        af[a][kk] = *(const bf16x8*)(Ab + r * 128 + ((((kk << 2) + g) ^ (r & 7)) << 4));
    }
    __builtin_amdgcn_s_barrier();
    __builtin_amdgcn_s_setprio(1);
#pragma unroll
    for (int a = 2; a < 4; ++a)
#pragma unroll
      for (int ni = 0; ni < 4; ++ni) {
        acc[a][ni] = MFMA16(af[a][0], bq[ni][0], acc[a][ni]);
        acc[a][ni] = MFMA16(af[a][1], bq[ni][1], acc[a][ni]);
      }
    __builtin_amdgcn_s_setprio(0);
    __builtin_amdgcn_s_barrier();

    // -------- phase 2: stage A0(t+2); MFMA a=4,5; vmcnt validates B(t+1) --------
    if (t < 14) stage(A0p, As[cur], k2);
    __builtin_amdgcn_s_barrier();
    __builtin_amdgcn_s_setprio(1);
#pragma unroll
    for (int a = 4; a < 6; ++a)
#pragma unroll
      for (int ni = 0; ni < 4; ++ni) {
        acc[a][ni] = MFMA16(af[a][0], bq[ni][0], acc[a][ni]);
        acc[a][ni] = MFMA16(af[a][1], bq[ni][1], acc[a][ni]);
      }
    __builtin_amdgcn_s_setprio(0);
    if (t < 14) asm volatile("s_waitcnt vmcnt(2)" ::: "memory");  // allow A0(t+2) in flight
    else        asm volatile("s_waitcnt vmcnt(0)" ::: "memory");  // tail: nothing newer
    __builtin_amdgcn_s_barrier();

    // -------- phase 3: stage A1(t+2); MFMA a=6,7; re-read bq<-B(t+1); vmcnt validates A(t+1) --------
    if (t < 14) stage(A1p, As[cur] + 16384, k2);
    __builtin_amdgcn_s_barrier();
    __builtin_amdgcn_s_setprio(1);
#pragma unroll
    for (int a = 6; a < 8; ++a)
#pragma unroll
      for (int ni = 0; ni < 4; ++ni) {
        acc[a][ni] = MFMA16(af[a][0], bq[ni][0], acc[a][ni]);
        acc[a][ni] = MFMA16(af[a][1], bq[ni][1], acc[a][ni]);
      }
    __builtin_amdgcn_s_setprio(0);
    if (t < 15) {  // bq <- B(t+1) frags (validated by p2's vmcnt+barrier; SSA rename)
      const unsigned char* Bb = Bs[nxt] + bhalf;
#pragma unroll
      for (int b = 0; b < 4; ++b) {
        const int r = brow + b * 16 + colL;
#pragma unroll
        for (int kk = 0; kk < 2; ++kk)
          bq[b][kk] = *(const bf16x8*)(Bb + r * 128 + ((((kk << 2) + g) ^ (r & 7)) << 4));
      }
    }
    if (t < 14) asm volatile("s_waitcnt vmcnt(4)" ::: "memory");  // allow A(t+2) in flight
    else        asm volatile("s_waitcnt vmcnt(0)" ::: "memory");
    __builtin_amdgcn_s_barrier();
  }

  // epilogue: C/D layout col=lane&15, row=(lane>>4)*4+reg; scatter to Q/K/V
#pragma unroll
  for (int ni = 0; ni < 4; ++ni) {
    const int Cn = n0 + wn * 64 + ni * 16 + colL;
    const float bv = bias[Cn];
    const int sx = Cn >> 10, h = (Cn >> 6) & 15, d = Cn & 63;
    __bf16* dst = (sx == 0) ? qo : (sx == 1 ? ko : vo);
    const float mul = (sx == 0) ? 0.125f : 1.0f;  // fold SCALE into Q (exact pow2)
#pragma unroll
    for (int mi = 0; mi < 8; ++mi) {
#pragma unroll
      for (int j = 0; j < 4; ++j) {
        const int Rm = m0 + wm * 128 + mi * 16 + (g << 2) + j;
        const int bb = Rm >> 11, tt = Rm & 2047;
        dst[(((size_t)bb * 16 + h) * 2048 + tt) * 64 + d] = (__bf16)((acc[mi][ni][j] + bv) * mul);
      }
    }
  }
}

// ---------------- 128^2 m97-style GEMM (out-proj): C = A*Bw^T + bias, fp32 out ----
__global__ __launch_bounds__(256) void gemm_bt_out(
    const __bf16* __restrict__ A, const __bf16* __restrict__ Bw,
    const float* __restrict__ bias, int M, int N, int K,
    float* __restrict__ outF) {
  __shared__ __align__(16) unsigned char As[128 * 128];
  __shared__ __align__(16) unsigned char Bs[128 * 128];
  const int tid = threadIdx.x;
  const int lane = tid & 63;
  const int wid = tid >> 6;
  const int wr = wid >> 1, wc = wid & 1;
  const int colL = lane & 15, g = lane >> 4;
  const int m0 = blockIdx.x * 128, n0 = blockIdx.y * 128;

  f32x4 acc[4][4] = {};

  const int nK = K >> 6;
  for (int ks = 0; ks < nK; ++ks) {
    const int k0 = ks << 6;
    __syncthreads();
#pragma unroll
    for (int it = 0; it < 4; ++it) {
      int c = tid + (it << 8);
      int row = c >> 3, p = c & 7;
      int q = p ^ (row & 7);
      GLOAD16(A + (size_t)(m0 + row) * K + (k0 + (q << 3)), As + c * 16);
      GLOAD16(Bw + (size_t)(n0 + row) * K + (k0 + (q << 3)), Bs + c * 16);
    }
    __syncthreads();
#pragma unroll
    for (int kk = 0; kk < 2; ++kk) {
      bf16x8 af[4], bf[4];
      const int slot = (kk << 2) + g;
#pragma unroll
      for (int mi = 0; mi < 4; ++mi) {
        int r = (wr << 6) + (mi << 4) + colL;
        af[mi] = *(const bf16x8*)(As + r * 128 + ((slot ^ (r & 7)) << 4));
      }
#pragma unroll
      for (int ni = 0; ni < 4; ++ni) {
        int r = (wc << 6) + (ni << 4) + colL;
        bf[ni] = *(const bf16x8*)(Bs + r * 128 + ((slot ^ (r & 7)) << 4));
      }
#pragma unroll
      for (int mi = 0; mi < 4; ++mi)
#pragma unroll
        for (int ni = 0; ni < 4; ++ni)
          acc[mi][ni] = MFMA16(af[mi], bf[ni], acc[mi][ni]);
    }
  }

#pragma unroll
  for (int ni = 0; ni < 4; ++ni) {
    const int Cn = n0 + (wc << 6) + (ni << 4) + colL;
    const float bv = bias[Cn];
#pragma unroll
    for (int mi = 0; mi < 4; ++mi) {
#pragma unroll
      for (int j = 0; j < 4; ++j) {
        const int Rm = m0 + (wr << 6) + (mi << 4) + (g << 2) + j;
        outF[(size_t)Rm * N + Cn] = acc[mi][ni][j] + bv;
      }
    }
  }
}

// ---------------- V [bh, t, 64] -> Vt [bh, 64, t] (64x64 tiles via LDS) ----------------
__global__ __launch_bounds__(256) void transpose_v(const __bf16* __restrict__ Vb,
                                                   __bf16* __restrict__ Vt) {
  const int blk = blockIdx.x;
  const int bh = blk >> 5;
  const int t0 = (blk & 31) << 6;
  __shared__ __align__(16) __bf16 ts[64][72];
  const int tid = threadIdx.x;
  const __bf16* src = Vb + ((size_t)bh * 2048 + t0) * 64;
#pragma unroll
  for (int it = 0; it < 2; ++it) {
    int c = tid + (it << 8);
    int r = c >> 3, q8 = (c & 7) << 3;
    *(bf16x8*)&ts[r][q8] = *(const bf16x8*)(src + r * 64 + q8);
  }
  __syncthreads();
  __bf16* dst = Vt + (size_t)bh * 64 * 2048 + t0;
#pragma unroll
  for (int it = 0; it < 2; ++it) {
    int c = tid + (it << 8);
    int d = c >> 3, j8 = (c & 7) << 3;
    bf16x8 o;
#pragma unroll
    for (int e = 0; e < 8; ++e) o[e] = ts[j8 + e][d];
    *(bf16x8*)(dst + (size_t)d * 2048 + j8) = o;
  }
}

// ---------------- windowed attention ----------------
__global__ __launch_bounds__(256) void attn_win(const __bf16* __restrict__ Qb,
                                                const __bf16* __restrict__ Kb,
                                                const __bf16* __restrict__ Vt,
                                                __bf16* __restrict__ Ob) {
  const int bh = blockIdx.x >> 5;
  const int qb = blockIdx.x & 31;
  const int b = bh >> 4, h = bh & 15;
  __shared__ __align__(16) unsigned char Qs[64 * 128];
  __shared__ __align__(16) unsigned char Ks[128 * 128];
  __shared__ __align__(16) unsigned char Vs[64 * 256];
  __shared__ __align__(16) unsigned char Ps[4 * 16 * 272];
  const int tid = threadIdx.x;
  const int lane = tid & 63;
  const int w = tid >> 6;
  const int colL = lane & 15, g = lane >> 4;
  const __bf16* Qg = Qb + (size_t)bh * 2048 * 64;
  const __bf16* Kg = Kb + (size_t)bh * 2048 * 64;
  const __bf16* Vg = Vt + (size_t)bh * 64 * 2048;
  const int t0 = qb * 64 - 64;

#pragma unroll
  for (int it = 0; it < 2; ++it) {
    int c = tid + (it << 8);
    int r = c >> 3, p = c & 7, q = p ^ (r & 7);
    GLOAD16(Qg + (size_t)(qb * 64 + r) * 64 + (q << 3), Qs + c * 16);
  }
#pragma unroll
  for (int it = 0; it < 4; ++it) {
    int c = tid + (it << 8);
    int r = c >> 3, p = c & 7, q = p ^ (r & 7);
    int tok = t0 + r;
    tok = tok < 0 ? 0 : tok;
    GLOAD16(Kg + (size_t)tok * 64 + (q << 3), Ks + c * 16);
  }
#pragma unroll
  for (int it = 0; it < 4; ++it) {
    int c = tid + (it << 8);
    int r = c >> 4, p = c & 15, q = p ^ (r & 7);
    int tk = t0 + (q << 3);
    tk = tk < 0 ? 0 : tk;
    GLOAD16(Vg + (size_t)r * 2048 + tk, Vs + c * 16);
  }
  __syncthreads();

  f32x4 sc[8] = {};
  bf16x8 qf[2];
#pragma unroll
  for (int kk = 0; kk < 2; ++kk) {
    int r = (w << 4) + colL;
    int slot = (kk << 2) + g;
    qf[kk] = *(const bf16x8*)(Qs + r * 128 + ((slot ^ (r & 7)) << 4));
  }
#pragma unroll
  for (int ni = 0; ni < 8; ++ni) {
#pragma unroll
    for (int kk = 0; kk < 2; ++kk) {
      int r = (ni << 4) + colL;
      int slot = (kk << 2) + g;
      bf16x8 kf = *(const bf16x8*)(Ks + r * 128 + ((slot ^ (r & 7)) << 4));
      sc[ni] = MFMA16(qf[kk], kf, sc[ni]);
    }
  }

  float mx[4], sm[4];
#pragma unroll
  for (int j = 0; j < 4; ++j) mx[j] = -3.0e38f;
#pragma unroll
  for (int ni = 0; ni < 8; ++ni) {
#pragma unroll
    for (int j = 0; j < 4; ++j) {
      const int qi = (w << 4) + (g << 2) + j;
      const int ki = (ni << 4) + colL;
      const bool valid = (ki > qi) && (ki <= qi + 64) && (qb > 0 || ki >= 64);
      if (!valid) sc[ni][j] = -3.0e38f;
      mx[j] = fmaxf(mx[j], sc[ni][j]);
    }
  }
#pragma unroll
  for (int j = 0; j < 4; ++j) {
    mx[j] = fmaxf(mx[j], __shfl_xor(mx[j], 1));
    mx[j] = fmaxf(mx[j], __shfl_xor(mx[j], 2));
    mx[j] = fmaxf(mx[j], __shfl_xor(mx[j], 4));
    mx[j] = fmaxf(mx[j], __shfl_xor(mx[j], 8));
    sm[j] = 0.0f;
  }
  unsigned char* ps = Ps + w * (16 * 272);
#pragma unroll
  for (int ni = 0; ni < 8; ++ni) {
#pragma unroll
    for (int j = 0; j < 4; ++j) {
      float p = __expf(sc[ni][j] - mx[j]);
      sm[j] += p;
      *(__bf16*)(ps + ((g << 2) + j) * 272 + (((ni << 4) + colL) << 1)) = (__bf16)p;
    }
  }
#pragma unroll
  for (int j = 0; j < 4; ++j) {
    sm[j] += __shfl_xor(sm[j], 1);
    sm[j] += __shfl_xor(sm[j], 2);
    sm[j] += __shfl_xor(sm[j], 4);
    sm[j] += __shfl_xor(sm[j], 8);
  }
  __syncthreads();

  f32x4 o[4] = {};
#pragma unroll
  for (int step = 0; step < 4; ++step) {
    bf16x8 pf = *(const bf16x8*)(ps + colL * 272 + (step << 6) + (g << 4));
#pragma unroll
    for (int dt = 0; dt < 4; ++dt) {
      int r = (dt << 4) + colL;
      int slot = (step << 2) + g;
      bf16x8 vf = *(const bf16x8*)(Vs + r * 256 + ((slot ^ (r & 7)) << 4));
      o[dt] = MFMA16(pf, vf, o[dt]);
    }
  }

  float rinv[4];
#pragma unroll
  for (int j = 0; j < 4; ++j) rinv[j] = 1.0f / sm[j];
#pragma unroll
  for (int dt = 0; dt < 4; ++dt) {
#pragma unroll
    for (int j = 0; j < 4; ++j) {
      const int t = qb * 64 + (w << 4) + (g << 2) + j;
      Ob[((size_t)b * 2048 + t) * 1024 + h * 64 + (dt << 4) + colL] =
          (__bf16)(o[dt][j] * rinv[j]);
    }
  }
}

extern "C" void kernel_launch(void* const* d_in, const int* in_sizes, int n_in,
                              void* d_out, int out_size, void* d_ws, size_t ws_size,
                              hipStream_t stream) {
  const float* x = (const float*)d_in[0];     // [2,2048,1024]
  const float* Wqkv = (const float*)d_in[1];  // [3072,1024]
  const float* bqkv = (const float*)d_in[2];  // [3072]
  const float* Wout = (const float*)d_in[3];  // [1024,1024]
  const float* bout = (const float*)d_in[4];  // [1024]
  float* out = (float*)d_out;                 // [2,2048,1024] fp32

  __bf16* xb = (__bf16*)d_ws;             // 4194304
  __bf16* Wqkvb = xb + 4194304;           // 3145728
  __bf16* Woutb = Wqkvb + 3145728;        // 1048576
  __bf16* Qb = Woutb + 1048576;           // 4194304 each: [B,H,2048,64]
  __bf16* Kb = Qb + 4194304;
  __bf16* Vb = Kb + 4194304;
  __bf16* Vtb = Vb + 4194304;             // [B,H,64,2048]
  __bf16* AOb = Vtb + 4194304;            // attn out [B,2048,1024]

  cvt3<<<4096, 256, 0, stream>>>(x, Wqkv, Wout, xb, Wqkvb, Woutb);
  gemm256_qkv<<<192, 512, 0, stream>>>(xb, Wqkvb, bqkv, Qb, Kb, Vb);
  transpose_v<<<1024, 256, 0, stream>>>(Vb, Vtb);
  attn_win<<<1024, 256, 0, stream>>>(Qb, Kb, Vtb, AOb);
  gemm_bt_out<<<dim3(32, 8), 256, 0, stream>>>(AOb, Woutb, bout, 4096, 1024, 1024, out);
}

// Round 4
// 86.986 us; speedup vs baseline: 1.0780x; 1.0780x over previous
//
#include <hip/hip_runtime.h>
#include <hip/hip_bf16.h>

// LocalCausalAttention: B=2, N=2048, D=1024, H=16, DH=64, WINDOW=64
// out = ( softmax(mask(QK^T*0.125)) V ) Wout^T + bout,  QKV = x Wqkv^T + bqkv
//
// R4: BK=128 amortization experiment.
//   Evidence: R1 (m97-style), R2 (drain-0 deep-phase), R3 (counted-vmcnt deep-phase)
//   ALL give ~55us / 460 TF for the QKV GEMM -> per-K-step fixed cost (~1100cy) is
//   schedule-invariant; amortize it with 2x MFMA per step instead.
//   gemm128: 128x128 tile, BK=128, single-buffer 64KB LDS -> 2 blocks/CU co-resident
//   (m114 implicit overlap hides the drain), 2-barrier loop, 16B global_load_lds,
//   16-slot XOR swizzle (slot ^ (row&7)).
//   transpose_v deleted: QKV epilogue writes V directly transposed into Vt.

typedef __attribute__((ext_vector_type(8))) __bf16 bf16x8;
typedef __attribute__((ext_vector_type(4))) float f32x4;

#define GLOAD16(g, l)                                              \
  __builtin_amdgcn_global_load_lds(                                \
      (const __attribute__((address_space(1))) void*)(g),          \
      (__attribute__((address_space(3))) void*)(l), 16, 0, 0)

#define MFMA16(a, b, c) __builtin_amdgcn_mfma_f32_16x16x32_bf16((a), (b), (c), 0, 0, 0)

// ---------------- fused fp32 -> bf16 convert (x, Wqkv, Wout) ----------------
__global__ __launch_bounds__(256) void cvt3(const float* __restrict__ x,
                                            const float* __restrict__ wqkv,
                                            const float* __restrict__ wout,
                                            __bf16* __restrict__ xb,
                                            __bf16* __restrict__ wqkvb,
                                            __bf16* __restrict__ woutb) {
  const int blk = blockIdx.x;
  const float* src;
  __bf16* dst;
  int i;
  if (blk < 2048) {            // x: 4194304 elems
    src = x; dst = xb; i = (blk * 256 + (int)threadIdx.x) * 8;
  } else if (blk < 3584) {     // Wqkv: 3145728 elems
    src = wqkv; dst = wqkvb; i = ((blk - 2048) * 256 + (int)threadIdx.x) * 8;
  } else {                     // Wout: 1048576 elems
    src = wout; dst = woutb; i = ((blk - 3584) * 256 + (int)threadIdx.x) * 8;
  }
  f32x4 a = *(const f32x4*)(src + i);
  f32x4 b = *(const f32x4*)(src + i + 4);
  bf16x8 o;
  o[0] = (__bf16)a[0]; o[1] = (__bf16)a[1]; o[2] = (__bf16)a[2]; o[3] = (__bf16)a[3];
  o[4] = (__bf16)b[0]; o[5] = (__bf16)b[1]; o[6] = (__bf16)b[2]; o[7] = (__bf16)b[3];
  *(bf16x8*)(dst + i) = o;
}

// ---------------- 128^2 BK=128 GEMM: C[m,n] = sum_k A[m,k]*Bw[n,k] + bias[n] ----
// 4 waves (2x2), per-wave 64x64 output (4x4 frags). Single-buffer 64KB LDS.
// MODE 0: scatter bf16 to Q(*0.125)/K [B,H,2048,64] and V TRANSPOSED [B,H,64,2048].
// MODE 1: fp32 out row-major + bias.
template <int MODE>
__global__ __launch_bounds__(256) void gemm128(
    const __bf16* __restrict__ A, const __bf16* __restrict__ Bw,
    const float* __restrict__ bias, int M, int N, int K,
    float* __restrict__ outF,
    __bf16* __restrict__ qo, __bf16* __restrict__ ko, __bf16* __restrict__ vt) {
  __shared__ __align__(16) unsigned char As[128 * 256];  // 128 rows x 128 bf16 (256B)
  __shared__ __align__(16) unsigned char Bs[128 * 256];
  const int tid = threadIdx.x;
  const int lane = tid & 63;
  const int wid = tid >> 6;
  const int wr = wid >> 1, wc = wid & 1;
  const int colL = lane & 15, g = lane >> 4;
  const int m0 = blockIdx.x * 128, n0 = blockIdx.y * 128;

  f32x4 acc[4][4] = {};

  const int nK = K >> 7;  // BK=128
  for (int ks = 0; ks < nK; ++ks) {
    const int k0 = ks << 7;
    __syncthreads();  // prior compute done before overwrite (WAR)
#pragma unroll
    for (int it = 0; it < 8; ++it) {
      int c = tid + (it << 8);       // 0..2047 : 128 rows x 16 chunks of 16B
      int row = c >> 4, p = c & 15;
      int q = p ^ (row & 7);         // inverse-swizzled source, linear LDS dest
      GLOAD16(A + (size_t)(m0 + row) * K + (k0 + (q << 3)), As + c * 16);
      GLOAD16(Bw + (size_t)(n0 + row) * K + (k0 + (q << 3)), Bs + c * 16);
    }
    __syncthreads();  // drains vmcnt (2 blocks/CU cover the stall)
#pragma unroll
    for (int kk = 0; kk < 4; ++kk) {
      bf16x8 af[4], bf[4];
      const int slot = (kk << 2) + g;  // chunk index 0..15
#pragma unroll
      for (int mi = 0; mi < 4; ++mi) {
        int r = (wr << 6) + (mi << 4) + colL;
        af[mi] = *(const bf16x8*)(As + r * 256 + ((slot ^ (r & 7)) << 4));
      }
#pragma unroll
      for (int ni = 0; ni < 4; ++ni) {
        int r = (wc << 6) + (ni << 4) + colL;
        bf[ni] = *(const bf16x8*)(Bs + r * 256 + ((slot ^ (r & 7)) << 4));
      }
#pragma unroll
      for (int mi = 0; mi < 4; ++mi)
#pragma unroll
        for (int ni = 0; ni < 4; ++ni)
          acc[mi][ni] = MFMA16(af[mi], bf[ni], acc[mi][ni]);
    }
  }

  // epilogue: C/D layout col=lane&15, row=(lane>>4)*4+reg (m89-verified)
#pragma unroll
  for (int ni = 0; ni < 4; ++ni) {
    const int Cn = n0 + (wc << 6) + (ni << 4) + colL;
    const float bv = bias[Cn];
    if (MODE == 0) {
      const int sx = Cn >> 10, h = (Cn >> 6) & 15, d = Cn & 63;
      const float mul = (sx == 0) ? 0.125f : 1.0f;  // fold SCALE into Q (exact pow2)
#pragma unroll
      for (int mi = 0; mi < 4; ++mi) {
#pragma unroll
        for (int j = 0; j < 4; ++j) {
          const int Rm = m0 + (wr << 6) + (mi << 4) + (g << 2) + j;
          const int bb = Rm >> 11, tt = Rm & 2047;
          const float v = (acc[mi][ni][j] + bv) * mul;
          if (sx == 2) {
            // V written TRANSPOSED: Vt[bh][d][t]  (L2 merges; line filled by wave)
            vt[(((size_t)bb * 16 + h) * 64 + d) * 2048 + tt] = (__bf16)v;
          } else {
            __bf16* dst = (sx == 0) ? qo : ko;
            dst[(((size_t)bb * 16 + h) * 2048 + tt) * 64 + d] = (__bf16)v;
          }
        }
      }
    } else {
#pragma unroll
      for (int mi = 0; mi < 4; ++mi) {
#pragma unroll
        for (int j = 0; j < 4; ++j) {
          const int Rm = m0 + (wr << 6) + (mi << 4) + (g << 2) + j;
          outF[(size_t)Rm * N + Cn] = acc[mi][ni][j] + bv;
        }
      }
    }
  }
}

// ---------------- windowed attention ----------------
// grid: (b*16+h)*32 + qb.  4 waves x 16 query rows.  Key tile = 128 tokens from qb*64-64.
__global__ __launch_bounds__(256) void attn_win(const __bf16* __restrict__ Qb,
                                                const __bf16* __restrict__ Kb,
                                                const __bf16* __restrict__ Vt,
                                                __bf16* __restrict__ Ob) {
  const int bh = blockIdx.x >> 5;
  const int qb = blockIdx.x & 31;
  const int b = bh >> 4, h = bh & 15;
  __shared__ __align__(16) unsigned char Qs[64 * 128];
  __shared__ __align__(16) unsigned char Ks[128 * 128];
  __shared__ __align__(16) unsigned char Vs[64 * 256];      // Vt tile [64 d][128 kk]
  __shared__ __align__(16) unsigned char Ps[4 * 16 * 272];  // per-wave P, 272B rows
  const int tid = threadIdx.x;
  const int lane = tid & 63;
  const int w = tid >> 6;
  const int colL = lane & 15, g = lane >> 4;
  const __bf16* Qg = Qb + (size_t)bh * 2048 * 64;
  const __bf16* Kg = Kb + (size_t)bh * 2048 * 64;
  const __bf16* Vg = Vt + (size_t)bh * 64 * 2048;
  const int t0 = qb * 64 - 64;

#pragma unroll
  for (int it = 0; it < 2; ++it) {  // Q: 64 rows x 8 slots
    int c = tid + (it << 8);
    int r = c >> 3, p = c & 7, q = p ^ (r & 7);
    GLOAD16(Qg + (size_t)(qb * 64 + r) * 64 + (q << 3), Qs + c * 16);
  }
#pragma unroll
  for (int it = 0; it < 4; ++it) {  // K: 128 rows x 8 slots
    int c = tid + (it << 8);
    int r = c >> 3, p = c & 7, q = p ^ (r & 7);
    int tok = t0 + r;
    tok = tok < 0 ? 0 : tok;  // qb==0: clamp, masked later
    GLOAD16(Kg + (size_t)tok * 64 + (q << 3), Ks + c * 16);
  }
#pragma unroll
  for (int it = 0; it < 4; ++it) {  // Vt: 64 rows x 16 slots
    int c = tid + (it << 8);
    int r = c >> 4, p = c & 15, q = p ^ (r & 7);
    int tk = t0 + (q << 3);
    tk = tk < 0 ? 0 : tk;  // clamped cols have P=0
    GLOAD16(Vg + (size_t)r * 2048 + tk, Vs + c * 16);
  }
  __syncthreads();

  f32x4 sc[8] = {};
  bf16x8 qf[2];
#pragma unroll
  for (int kk = 0; kk < 2; ++kk) {
    int r = (w << 4) + colL;
    int slot = (kk << 2) + g;
    qf[kk] = *(const bf16x8*)(Qs + r * 128 + ((slot ^ (r & 7)) << 4));
  }
#pragma unroll
  for (int ni = 0; ni < 8; ++ni) {
#pragma unroll
    for (int kk = 0; kk < 2; ++kk) {
      int r = (ni << 4) + colL;
      int slot = (kk << 2) + g;
      bf16x8 kf = *(const bf16x8*)(Ks + r * 128 + ((slot ^ (r & 7)) << 4));
      sc[ni] = MFMA16(qf[kk], kf, sc[ni]);
    }
  }

  float mx[4], sm[4];
#pragma unroll
  for (int j = 0; j < 4; ++j) mx[j] = -3.0e38f;
#pragma unroll
  for (int ni = 0; ni < 8; ++ni) {
#pragma unroll
    for (int j = 0; j < 4; ++j) {
      const int qi = (w << 4) + (g << 2) + j;
      const int ki = (ni << 4) + colL;
      const bool valid = (ki > qi) && (ki <= qi + 64) && (qb > 0 || ki >= 64);
      if (!valid) sc[ni][j] = -3.0e38f;  // finite: avoids inf-inf NaN
      mx[j] = fmaxf(mx[j], sc[ni][j]);
    }
  }
#pragma unroll
  for (int j = 0; j < 4; ++j) {
    mx[j] = fmaxf(mx[j], __shfl_xor(mx[j], 1));
    mx[j] = fmaxf(mx[j], __shfl_xor(mx[j], 2));
    mx[j] = fmaxf(mx[j], __shfl_xor(mx[j], 4));
    mx[j] = fmaxf(mx[j], __shfl_xor(mx[j], 8));
    sm[j] = 0.0f;
  }
  unsigned char* ps = Ps + w * (16 * 272);
#pragma unroll
  for (int ni = 0; ni < 8; ++ni) {
#pragma unroll
    for (int j = 0; j < 4; ++j) {
      float p = __expf(sc[ni][j] - mx[j]);
      sm[j] += p;
      *(__bf16*)(ps + ((g << 2) + j) * 272 + (((ni << 4) + colL) << 1)) = (__bf16)p;
    }
  }
#pragma unroll
  for (int j = 0; j < 4; ++j) {
    sm[j] += __shfl_xor(sm[j], 1);
    sm[j] += __shfl_xor(sm[j], 2);
    sm[j] += __shfl_xor(sm[j], 4);
    sm[j] += __shfl_xor(sm[j], 8);
  }
  __syncthreads();

  f32x4 o[4] = {};
#pragma unroll
  for (int step = 0; step < 4; ++step) {
    bf16x8 pf = *(const bf16x8*)(ps + colL * 272 + (step << 6) + (g << 4));
#pragma unroll
    for (int dt = 0; dt < 4; ++dt) {
      int r = (dt << 4) + colL;
      int slot = (step << 2) + g;
      bf16x8 vf = *(const bf16x8*)(Vs + r * 256 + ((slot ^ (r & 7)) << 4));
      o[dt] = MFMA16(pf, vf, o[dt]);
    }
  }

  float rinv[4];
#pragma unroll
  for (int j = 0; j < 4; ++j) rinv[j] = 1.0f / sm[j];
#pragma unroll
  for (int dt = 0; dt < 4; ++dt) {
#pragma unroll
    for (int j = 0; j < 4; ++j) {
      const int t = qb * 64 + (w << 4) + (g << 2) + j;
      Ob[((size_t)b * 2048 + t) * 1024 + h * 64 + (dt << 4) + colL] =
          (__bf16)(o[dt][j] * rinv[j]);
    }
  }
}

extern "C" void kernel_launch(void* const* d_in, const int* in_sizes, int n_in,
                              void* d_out, int out_size, void* d_ws, size_t ws_size,
                              hipStream_t stream) {
  const float* x = (const float*)d_in[0];     // [2,2048,1024]
  const float* Wqkv = (const float*)d_in[1];  // [3072,1024]
  const float* bqkv = (const float*)d_in[2];  // [3072]
  const float* Wout = (const float*)d_in[3];  // [1024,1024]
  const float* bout = (const float*)d_in[4];  // [1024]
  float* out = (float*)d_out;                 // [2,2048,1024] fp32

  __bf16* xb = (__bf16*)d_ws;             // 4194304
  __bf16* Wqkvb = xb + 4194304;           // 3145728
  __bf16* Woutb = Wqkvb + 3145728;        // 1048576
  __bf16* Qb = Woutb + 1048576;           // 4194304 each: [B,H,2048,64]
  __bf16* Kb = Qb + 4194304;
  __bf16* Vtb = Kb + 4194304;             // [B,H,64,2048] (written transposed by gemm)
  __bf16* AOb = Vtb + 4194304;            // attn out [B,2048,1024]

  cvt3<<<4096, 256, 0, stream>>>(x, Wqkv, Wout, xb, Wqkvb, Woutb);
  gemm128<0><<<dim3(32, 24), 256, 0, stream>>>(xb, Wqkvb, bqkv, 4096, 3072, 1024,
                                               nullptr, Qb, Kb, Vtb);
  attn_win<<<1024, 256, 0, stream>>>(Qb, Kb, Vtb, AOb);
  gemm128<1><<<dim3(32, 8), 256, 0, stream>>>(AOb, Woutb, bout, 4096, 1024, 1024,
                                              out, nullptr, nullptr, nullptr);
}